// Round 6
// baseline (72.533 us; speedup 1.0000x reference)
//
#include <hip/hip_runtime.h>
#include <stdint.h>
#include <stddef.h>

#define E_DIM 1024

typedef __bf16 v8bf __attribute__((ext_vector_type(8)));
typedef float v4f __attribute__((ext_vector_type(4)));

__device__ __forceinline__ unsigned short f2bf(float x) {
  unsigned int u = __builtin_bit_cast(unsigned int, x);
  u += 0x7fffu + ((u >> 16) & 1u);
  return (unsigned short)(u >> 16);
}

// XOR swizzle for LDS rows >= 128B (else natural 16B-chunk spread = b128 floor).
template <int RB>
__device__ __forceinline__ int swz(int r, int c) {
  if constexpr (RB >= 128) return c ^ ((r & 7) << 4);
  else return c;
}

// bf16 global tile (ROWS x BK) -> LDS via global_load_lds (async, source pre-swizzled).
template <int ROWS, int BK>
__device__ __forceinline__ void stageg(const char* __restrict__ G, int g0, int ldg,
                                       int k0, char* L, int tid) {
  constexpr int RB = BK * 2;
  constexpr int ITERS = (ROWS * RB) / 4096;
  const int wid = tid >> 6, lane = tid & 63;
#pragma unroll
  for (int it = 0; it < ITERS; ++it) {
    int lbase = it * 4096 + wid * 1024;
    int lin = lbase + lane * 16;
    int r = lin / RB, cb = lin % RB;
    int gcb = swz<RB>(r, cb);
    const char* g = G + ((size_t)(g0 + r) * ldg + k0) * 2 + gcb;
    __builtin_amdgcn_global_load_lds((const __attribute__((address_space(1))) void*)g,
                                     (__attribute__((address_space(3))) void*)(L + lbase),
                                     16, 0, 0);
  }
}

// fp32 operand: T14 split. Phase 1: issue float4 loads into regs.
template <int ROWS, int BK>
__device__ __forceinline__ void regload(const float* __restrict__ G, int g0, int ldg,
                                        int k0, int tid, float4 (&r)[(ROWS * BK) / 1024]) {
  constexpr int C4 = BK / 4;
#pragma unroll
  for (int p = 0; p < (ROWS * BK) / 1024; ++p) {
    int i4 = p * 256 + tid;
    int row = i4 / C4, c4 = i4 % C4;
    r[p] = *reinterpret_cast<const float4*>(G + (size_t)(g0 + row) * ldg + k0 + c4 * 4);
  }
}

// Phase 2 (after compute): cvt fp32->bf16 and ds_write into LDS (swizzled offset).
template <int ROWS, int BK>
__device__ __forceinline__ void cvtwrite(const float4 (&r)[(ROWS * BK) / 1024],
                                         char* L, int tid) {
  constexpr int C4 = BK / 4, RB = BK * 2;
#pragma unroll
  for (int p = 0; p < (ROWS * BK) / 1024; ++p) {
    int i4 = p * 256 + tid;
    int row = i4 / C4, c4 = i4 % C4;
    ushort4 u;
    u.x = f2bf(r[p].x); u.y = f2bf(r[p].y); u.z = f2bf(r[p].z); u.w = f2bf(r[p].w);
    *reinterpret_cast<ushort4*>(L + row * RB + swz<RB>(row, c4 * 8)) = u;
  }
}

template <int RB>
__device__ __forceinline__ v8bf frag_bf16(const char* L, int r, int kelem) {
  int o = swz<RB>(r, kelem * 2);
  return *(const v8bf*)(L + r * RB + o);
}

// one K-tile of MFMA work from (bf16) LDS buffers
template <int BM, int BN, int BK, int FM, int FN>
__device__ __forceinline__ void compute_tile(const char* Al, const char* Bl,
                                             v4f (&acc)[FM][FN],
                                             int wr, int wc, int lr, int kg) {
  constexpr int RBA = BK * 2, RBB = BK * 2;
  constexpr int TMW = BM / 2, TNW = BN / 2;
#pragma unroll
  for (int kk = 0; kk < BK / 32; ++kk) {
    const int ke = kk * 32 + kg * 8;
    v8bf a[FM], b[FN];
#pragma unroll
    for (int mi = 0; mi < FM; ++mi)
      a[mi] = frag_bf16<RBA>(Al, wr * TMW + mi * 16 + lr, ke);
#pragma unroll
    for (int ni = 0; ni < FN; ++ni)
      b[ni] = frag_bf16<RBB>(Bl, wc * TNW + ni * 16 + lr, ke);
#pragma unroll
    for (int mi = 0; mi < FM; ++mi)
#pragma unroll
      for (int ni = 0; ni < FN; ++ni)
        acc[mi][ni] = __builtin_amdgcn_mfma_f32_16x16x32_bf16(a[mi], b[ni], acc[mi][ni], 0, 0, 0);
  }
}

// ---- prep1: transpose+cvt Wv (1024x512 f32 -> 512x1024 bf16)  [blocks 0..511]
//             + matvec b1 = Wiv@bv + biv                        [blocks 512..767]
__global__ __launch_bounds__(256) void prep1(const float* __restrict__ Wv,
                                             unsigned short* __restrict__ WvT,
                                             const float* __restrict__ Wiv,
                                             const float* __restrict__ bv,
                                             const float* __restrict__ biv,
                                             float* __restrict__ b1) {
  int bid = blockIdx.x;
  if (bid < 512) {
    __shared__ float tile[32][33];
    const int R = 1024, C = 512;
    int nbx = C >> 5;
    int bx = bid % nbx, by = bid / nbx;
    int tx = threadIdx.x & 31, ty = threadIdx.x >> 5;
#pragma unroll
    for (int i = 0; i < 32; i += 8)
      tile[ty + i][tx] = Wv[(size_t)(by * 32 + ty + i) * C + bx * 32 + tx];
    __syncthreads();
#pragma unroll
    for (int i = 0; i < 32; i += 8)
      WvT[(size_t)(bx * 32 + ty + i) * R + by * 32 + tx] = f2bf(tile[tx][ty + i]);
  } else {
    int r = (bid - 512) * 4 + (threadIdx.x >> 6);
    int lane = threadIdx.x & 63;
    float s = 0.f;
    for (int c = lane; c < 1024; c += 64) s += Wiv[(size_t)r * 1024 + c] * bv[c];
#pragma unroll
    for (int off = 32; off; off >>= 1) s += __shfl_down(s, off);
    if (lane == 0) b1[r] = s + biv[r];
  }
}

// ---- bt-GEMM, double-buffered bf16 LDS; fp32 operands reg-staged (T14 split),
// bf16 operands via global_load_lds. One barrier per K-step; loads for t+1 get
// a full compute-phase latency window. K/BK must be even.
template <int BM, int BN, int BK, int FM, int FN, int OUTBF, int AF32, int BF32, int XCDSWZ>
__global__ __launch_bounds__(256) void gemm_bt(const void* __restrict__ Ag,
                                               const void* __restrict__ Bg,
                                               const float* __restrict__ bias,
                                               float* __restrict__ Cf,
                                               unsigned short* __restrict__ Cb,
                                               int M, int N, int K,
                                               const float* __restrict__ mvW,
                                               const float* __restrict__ mvx,
                                               const float* __restrict__ mvb,
                                               float* __restrict__ mvy) {
  __shared__ __align__(16) char Al0[BM * BK * 2];
  __shared__ __align__(16) char Al1[BM * BK * 2];
  __shared__ __align__(16) char Bl0[BN * BK * 2];
  __shared__ __align__(16) char Bl1[BN * BK * 2];
  const int nbn = N / BN;
  const int ngemm = nbn * (M / BM);
  int bid = blockIdx.x;
  const int tid = threadIdx.x;

  if (bid >= ngemm) {  // merged matvec tail
    int r = (bid - ngemm) * 4 + (tid >> 6);
    int lane = tid & 63;
    float s = 0.f;
    for (int c = lane; c < 1024; c += 64) s += mvW[(size_t)r * 1024 + c] * mvx[c];
#pragma unroll
    for (int off = 32; off; off >>= 1) s += __shfl_down(s, off);
    if (lane == 0) mvy[r] = s + mvb[r];
    return;
  }

  int bm_i, bn_i;
  if (XCDSWZ) {  // all 8 col-blocks of a row-band on one XCD (nbn == 8)
    int x = bid & 7, j = bid >> 3;
    bm_i = x + ((j >> 3) << 3);
    bn_i = j & 7;
  } else {
    bm_i = bid / nbn;
    bn_i = bid % nbn;
  }
  const int bm0 = bm_i * BM, bn0 = bn_i * BN;

  constexpr int TMW = BM / 2, TNW = BN / 2;
  const int lane = tid & 63;
  const int wid = tid >> 6;
  const int wr = wid >> 1, wc = wid & 1;
  const int lr = lane & 15;
  const int kg = lane >> 4;
  const char* Ac = (const char*)Ag;
  const char* Bc = (const char*)Bg;
  const float* Af = (const float*)Ag;
  const float* Bf = (const float*)Bg;

  v4f acc[FM][FN];
#pragma unroll
  for (int i = 0; i < FM; ++i)
#pragma unroll
    for (int j = 0; j < FN; ++j) acc[i][j] = 0.f;

  float4 ra[AF32 ? (BM * BK) / 1024 : 1];
  float4 rb[BF32 ? (BN * BK) / 1024 : 1];

  const int NT = K / BK;  // even

  // prologue: tile 0 into A0/B0
  if constexpr (AF32) regload<BM, BK>(Af, bm0, K, 0, tid, (float4(&)[(BM * BK) / 1024])ra);
  else                stageg<BM, BK>(Ac, bm0, K, 0, Al0, tid);
  if constexpr (BF32) regload<BN, BK>(Bf, bn0, K, 0, tid, (float4(&)[(BN * BK) / 1024])rb);
  else                stageg<BN, BK>(Bc, bn0, K, 0, Bl0, tid);
  if constexpr (AF32) cvtwrite<BM, BK>((float4(&)[(BM * BK) / 1024])ra, Al0, tid);
  if constexpr (BF32) cvtwrite<BN, BK>((float4(&)[(BN * BK) / 1024])rb, Bl0, tid);
  __syncthreads();

  for (int t = 0; t < NT; t += 2) {
    // phase even: prefetch t+1 -> A1/B1, compute t from A0/B0
    {  // t+1 < NT always (NT even)
      if constexpr (AF32) regload<BM, BK>(Af, bm0, K, (t + 1) * BK, tid, (float4(&)[(BM * BK) / 1024])ra);
      else                stageg<BM, BK>(Ac, bm0, K, (t + 1) * BK, Al1, tid);
      if constexpr (BF32) regload<BN, BK>(Bf, bn0, K, (t + 1) * BK, tid, (float4(&)[(BN * BK) / 1024])rb);
      else                stageg<BN, BK>(Bc, bn0, K, (t + 1) * BK, Bl1, tid);
    }
    __builtin_amdgcn_sched_barrier(0);
    compute_tile<BM, BN, BK, FM, FN>(Al0, Bl0, acc, wr, wc, lr, kg);
    {
      if constexpr (AF32) cvtwrite<BM, BK>((float4(&)[(BM * BK) / 1024])ra, Al1, tid);
      if constexpr (BF32) cvtwrite<BN, BK>((float4(&)[(BN * BK) / 1024])rb, Bl1, tid);
    }
    __syncthreads();

    // phase odd: prefetch t+2 -> A0/B0, compute t+1 from A1/B1
    if (t + 2 < NT) {
      if constexpr (AF32) regload<BM, BK>(Af, bm0, K, (t + 2) * BK, tid, (float4(&)[(BM * BK) / 1024])ra);
      else                stageg<BM, BK>(Ac, bm0, K, (t + 2) * BK, Al0, tid);
      if constexpr (BF32) regload<BN, BK>(Bf, bn0, K, (t + 2) * BK, tid, (float4(&)[(BN * BK) / 1024])rb);
      else                stageg<BN, BK>(Bc, bn0, K, (t + 2) * BK, Bl0, tid);
    }
    __builtin_amdgcn_sched_barrier(0);
    compute_tile<BM, BN, BK, FM, FN>(Al1, Bl1, acc, wr, wc, lr, kg);
    if (t + 2 < NT) {
      if constexpr (AF32) cvtwrite<BM, BK>((float4(&)[(BM * BK) / 1024])ra, Al0, tid);
      if constexpr (BF32) cvtwrite<BN, BK>((float4(&)[(BN * BK) / 1024])rb, Bl0, tid);
    }
    __syncthreads();
  }

  // epilogue: C/D frag mapping col = lane&15, row = (lane>>4)*4 + reg
#pragma unroll
  for (int ni = 0; ni < FN; ++ni) {
    int col = bn0 + wc * TNW + ni * 16 + lr;
    float bz = bias ? bias[col] : 0.f;
#pragma unroll
    for (int mi = 0; mi < FM; ++mi) {
      int row0 = bm0 + wr * TMW + mi * 16 + kg * 4;
#pragma unroll
      for (int r = 0; r < 4; ++r) {
        float v = acc[mi][ni][r] + bz;
        if (OUTBF) Cb[(size_t)(row0 + r) * N + col] = f2bf(v);
        else       Cf[(size_t)(row0 + r) * N + col] = v;
      }
    }
  }
}

extern "C" void kernel_launch(void* const* d_in, const int* in_sizes, int n_in,
                              void* d_out, int out_size, void* d_ws, size_t ws_size,
                              hipStream_t stream) {
  // softmax over singleton axis == 1  =>  out = x @ (Wo·Wiv·Wv)^T + [Wo·(Wiv·bv+biv)+bo]
  const float* vit = (const float*)d_in[1];
  const float* Wv  = (const float*)d_in[6];
  const float* bv  = (const float*)d_in[7];
  const float* ipw = (const float*)d_in[8];
  const float* ipb = (const float*)d_in[9];
  const float* Wo  = (const float*)d_in[10];
  const float* bo  = (const float*)d_in[11];
  const float* Wiv = ipw + 2 * E_DIM * E_DIM;
  const float* biv = ipb + 2 * E_DIM;

  char* ws = (char*)d_ws;
  unsigned short* WvTb = (unsigned short*)(ws);              // 512x1024 bf16
  unsigned short* Ttb  = (unsigned short*)(ws + (1 << 20));  // 512x1024 bf16 (T^T)
  unsigned short* Wcb  = (unsigned short*)(ws + (2 << 20));  // 1024x512 bf16
  float* b1 = (float*)(ws + (3 << 20));
  float* bc = (float*)(ws + (3 << 20) + 4096);

  // K1: transpose+cvt Wv -> WvT  ||  b1 = Wiv@bv + biv
  prep1<<<768, 256, 0, stream>>>(Wv, WvTb, Wiv, bv, biv, b1);

  // K2: T^T (512x1024) = WvT @ Wiv^T (B fp32 reg-staged), BK=64  ||  bc = Wo@b1 + bo
  gemm_bt<64, 64, 64, 2, 2, 1, 0, 1, 0><<<128 + 256, 256, 0, stream>>>(
      WvTb, Wiv, nullptr, nullptr, Ttb, 512, 1024, 1024, Wo, b1, bo, bc);

  // K3: Wc (1024x512) = Wo @ T (A fp32 reg-staged), BK=64
  gemm_bt<64, 64, 64, 2, 2, 1, 1, 0, 0><<<128, 256, 0, stream>>>(
      Wo, Ttb, nullptr, nullptr, Wcb, 1024, 512, 1024,
      nullptr, nullptr, nullptr, nullptr);

  // K4: out (16384x1024 f32) = vit @ Wc^T + bc (A fp32 reg-staged, XCD swizzle)
  gemm_bt<128, 128, 32, 4, 4, 0, 1, 0, 1><<<1024, 256, 0, stream>>>(
      vit, Wcb, bc, (float*)d_out, nullptr, 16384, 1024, 512,
      nullptr, nullptr, nullptr, nullptr);
}

// Round 7
// 62.810 us; speedup vs baseline: 1.1548x; 1.1548x over previous
//
#include <hip/hip_runtime.h>
#include <stdint.h>
#include <stddef.h>

#define E_DIM 1024

typedef __bf16 v8bf __attribute__((ext_vector_type(8)));
typedef float v4f __attribute__((ext_vector_type(4)));

__device__ __forceinline__ unsigned short f2bf(float x) {
  unsigned int u = __builtin_bit_cast(unsigned int, x);
  u += 0x7fffu + ((u >> 16) & 1u);
  return (unsigned short)(u >> 16);
}

// XOR swizzle for LDS rows >= 128B (involution; both-sides-or-neither).
template <int RB>
__device__ __forceinline__ int swz(int r, int c) {
  if constexpr (RB >= 128) return c ^ ((r & 7) << 4);
  else return c;
}

// bf16 global tile (ROWS x BK) -> LDS via global_load_lds, source pre-swizzled.
template <int ROWS, int BK>
__device__ __forceinline__ void stageg(const unsigned short* __restrict__ G, int g0,
                                       int ldg, int k0, char* L, int wid, int lane) {
  constexpr int RB = BK * 2;
  constexpr int ITERS = (ROWS * RB) / 4096;
#pragma unroll
  for (int it = 0; it < ITERS; ++it) {
    int lbase = it * 4096 + wid * 1024;   // wave-uniform LDS byte base
    int lin = lbase + lane * 16;
    int r = lin / RB, cb = lin % RB;
    int gcb = swz<RB>(r, cb);
    const char* g = (const char*)G + ((size_t)(g0 + r) * ldg + k0) * 2 + gcb;
    __builtin_amdgcn_global_load_lds((const __attribute__((address_space(1))) void*)g,
                                     (__attribute__((address_space(3))) void*)(L + lbase),
                                     16, 0, 0);
  }
}

template <int RB>
__device__ __forceinline__ v8bf frag_bf16(const char* L, int r, int kelem) {
  int o = swz<RB>(r, kelem * 2);
  return *(const v8bf*)(L + r * RB + o);
}

// one K-tile of MFMA work from bf16 LDS buffers
template <int BM, int BN, int BK, int FM, int FN>
__device__ __forceinline__ void compute_tile(const char* Al, const char* Bl,
                                             v4f (&acc)[FM][FN],
                                             int wr, int wc, int lr, int kg) {
  constexpr int RBA = BK * 2, RBB = BK * 2;
  constexpr int TMW = BM / 2, TNW = BN / 2;
#pragma unroll
  for (int kk = 0; kk < BK / 32; ++kk) {
    const int ke = kk * 32 + kg * 8;
    v8bf a[FM], b[FN];
#pragma unroll
    for (int mi = 0; mi < FM; ++mi)
      a[mi] = frag_bf16<RBA>(Al, wr * TMW + mi * 16 + lr, ke);
#pragma unroll
    for (int ni = 0; ni < FN; ++ni)
      b[ni] = frag_bf16<RBB>(Bl, wc * TNW + ni * 16 + lr, ke);
#pragma unroll
    for (int mi = 0; mi < FM; ++mi)
#pragma unroll
      for (int ni = 0; ni < FN; ++ni)
        acc[mi][ni] = __builtin_amdgcn_mfma_f32_16x16x32_bf16(a[mi], b[ni], acc[mi][ni], 0, 0, 0);
  }
}

__device__ __forceinline__ void cvt4(const float4* __restrict__ src,
                                     ushort4* __restrict__ dst, int i0) {
#pragma unroll
  for (int j = 0; j < 4; ++j) {
    int i = i0 + j * 256;
    float4 f = src[i];
    ushort4 u;
    u.x = f2bf(f.x); u.y = f2bf(f.y); u.z = f2bf(f.z); u.w = f2bf(f.w);
    dst[i] = u;
  }
}

// ---- prep1: transpose+cvt Wv [0,512) || matvec b1 [512,768)
//             || cvt vit [768,2816) || cvt Wiv [2816,3072) || cvt Wo [3072,3328)
__global__ __launch_bounds__(256) void prep1(const float* __restrict__ Wv,
                                             unsigned short* __restrict__ WvT,
                                             const float* __restrict__ Wiv,
                                             const float* __restrict__ bv,
                                             const float* __restrict__ biv,
                                             float* __restrict__ b1,
                                             const float* __restrict__ vit,
                                             unsigned short* __restrict__ Xb,
                                             unsigned short* __restrict__ Wivb,
                                             const float* __restrict__ Wo,
                                             unsigned short* __restrict__ Wob) {
  int bid = blockIdx.x;
  int tid = threadIdx.x;
  if (bid < 512) {
    __shared__ float tile[32][33];
    const int R = 1024, C = 512;
    int nbx = C >> 5;
    int bx = bid % nbx, by = bid / nbx;
    int tx = tid & 31, ty = tid >> 5;
#pragma unroll
    for (int i = 0; i < 32; i += 8)
      tile[ty + i][tx] = Wv[(size_t)(by * 32 + ty + i) * C + bx * 32 + tx];
    __syncthreads();
#pragma unroll
    for (int i = 0; i < 32; i += 8)
      WvT[(size_t)(bx * 32 + ty + i) * R + by * 32 + tx] = f2bf(tile[tx][ty + i]);
  } else if (bid < 768) {
    int r = (bid - 512) * 4 + (tid >> 6);
    int lane = tid & 63;
    float s = 0.f;
    for (int c = lane; c < 1024; c += 64) s += Wiv[(size_t)r * 1024 + c] * bv[c];
#pragma unroll
    for (int off = 32; off; off >>= 1) s += __shfl_down(s, off);
    if (lane == 0) b1[r] = s + biv[r];
  } else if (bid < 2816) {
    cvt4((const float4*)vit, (ushort4*)Xb, (bid - 768) * 1024 + tid);
  } else if (bid < 3072) {
    cvt4((const float4*)Wiv, (ushort4*)Wivb, (bid - 2816) * 1024 + tid);
  } else {
    cvt4((const float4*)Wo, (ushort4*)Wob, (bid - 3072) * 1024 + tid);
  }
}

// ---- bt-GEMM, all-bf16, depth-2 counted-vmcnt pipeline (4 loads/tile/wave).
template <int BM, int BN, int BK, int FM, int FN, int OUTBF, int XCDSWZ>
__global__ __launch_bounds__(256) void gemm_cv(const unsigned short* __restrict__ A,
                                               const unsigned short* __restrict__ B,
                                               const float* __restrict__ bias,
                                               float* __restrict__ Cf,
                                               unsigned short* __restrict__ Cb,
                                               int M, int N, int K,
                                               const float* __restrict__ mvW,
                                               const float* __restrict__ mvx,
                                               const float* __restrict__ mvb,
                                               float* __restrict__ mvy) {
  static_assert((BM + BN) * BK * 2 / 1024 / 4 == 4, "vmcnt(4) assumes 4 loads/tile/wave");
  __shared__ __align__(16) char Al0[BM * BK * 2];
  __shared__ __align__(16) char Al1[BM * BK * 2];
  __shared__ __align__(16) char Bl0[BN * BK * 2];
  __shared__ __align__(16) char Bl1[BN * BK * 2];
  const int nbn = N / BN;
  const int ngemm = nbn * (M / BM);
  int bid = blockIdx.x;
  const int tid = threadIdx.x;

  if (bid >= ngemm) {  // merged matvec tail
    int r = (bid - ngemm) * 4 + (tid >> 6);
    int lane = tid & 63;
    float s = 0.f;
    for (int c = lane; c < 1024; c += 64) s += mvW[(size_t)r * 1024 + c] * mvx[c];
#pragma unroll
    for (int off = 32; off; off >>= 1) s += __shfl_down(s, off);
    if (lane == 0) mvy[r] = s + mvb[r];
    return;
  }

  int bm_i, bn_i;
  if (XCDSWZ) {  // all 8 col-blocks of a row-band on one XCD (nbn == 8)
    int x = bid & 7, j = bid >> 3;
    bm_i = x + ((j >> 3) << 3);
    bn_i = j & 7;
  } else {
    bm_i = bid / nbn;
    bn_i = bid % nbn;
  }
  const int bm0 = bm_i * BM, bn0 = bn_i * BN;

  constexpr int TMW = BM / 2, TNW = BN / 2;
  const int lane = tid & 63;
  const int wid = tid >> 6;
  const int wr = wid >> 1, wc = wid & 1;
  const int lr = lane & 15;
  const int kg = lane >> 4;

  v4f acc[FM][FN];
#pragma unroll
  for (int i = 0; i < FM; ++i)
#pragma unroll
    for (int j = 0; j < FN; ++j) acc[i][j] = 0.f;

  const int NT = K / BK;  // even, >= 4

  // prologue: 2 tiles in flight (8 loads/wave outstanding)
  stageg<BM, BK>(A, bm0, K, 0, Al0, wid, lane);
  stageg<BN, BK>(B, bn0, K, 0, Bl0, wid, lane);
  stageg<BM, BK>(A, bm0, K, BK, Al1, wid, lane);
  stageg<BN, BK>(B, bn0, K, BK, Bl1, wid, lane);

  for (int t = 0; t < NT; t += 2) {
    // tile t from buf0; tile t+1's 4 loads stay in flight
    asm volatile("s_waitcnt vmcnt(4)" ::: "memory");
    __builtin_amdgcn_s_barrier();
    __builtin_amdgcn_sched_barrier(0);
    compute_tile<BM, BN, BK, FM, FN>(Al0, Bl0, acc, wr, wc, lr, kg);
    __builtin_amdgcn_sched_barrier(0);
    asm volatile("s_waitcnt lgkmcnt(0)" ::: "memory");
    __builtin_amdgcn_s_barrier();
    if (t + 2 < NT) {
      stageg<BM, BK>(A, bm0, K, (t + 2) * BK, Al0, wid, lane);
      stageg<BN, BK>(B, bn0, K, (t + 2) * BK, Bl0, wid, lane);
    }

    // tile t+1 from buf1; tile t+2's loads (if any) stay in flight
    if (t + 2 < NT) asm volatile("s_waitcnt vmcnt(4)" ::: "memory");
    else            asm volatile("s_waitcnt vmcnt(0)" ::: "memory");
    __builtin_amdgcn_s_barrier();
    __builtin_amdgcn_sched_barrier(0);
    compute_tile<BM, BN, BK, FM, FN>(Al1, Bl1, acc, wr, wc, lr, kg);
    __builtin_amdgcn_sched_barrier(0);
    asm volatile("s_waitcnt lgkmcnt(0)" ::: "memory");
    __builtin_amdgcn_s_barrier();
    if (t + 3 < NT) {
      stageg<BM, BK>(A, bm0, K, (t + 3) * BK, Al1, wid, lane);
      stageg<BN, BK>(B, bn0, K, (t + 3) * BK, Bl1, wid, lane);
    }
  }

  // epilogue: C/D frag mapping col = lane&15, row = (lane>>4)*4 + reg
#pragma unroll
  for (int ni = 0; ni < FN; ++ni) {
    int col = bn0 + wc * TNW + ni * 16 + lr;
    float bz = bias ? bias[col] : 0.f;
#pragma unroll
    for (int mi = 0; mi < FM; ++mi) {
      int row0 = bm0 + wr * TMW + mi * 16 + kg * 4;
#pragma unroll
      for (int r = 0; r < 4; ++r) {
        float v = acc[mi][ni][r] + bz;
        if (OUTBF) Cb[(size_t)(row0 + r) * N + col] = f2bf(v);
        else       Cf[(size_t)(row0 + r) * N + col] = v;
      }
    }
  }
}

extern "C" void kernel_launch(void* const* d_in, const int* in_sizes, int n_in,
                              void* d_out, int out_size, void* d_ws, size_t ws_size,
                              hipStream_t stream) {
  // softmax over singleton axis == 1  =>  out = x @ (Wo·Wiv·Wv)^T + [Wo·(Wiv·bv+biv)+bo]
  const float* vit = (const float*)d_in[1];
  const float* Wv  = (const float*)d_in[6];
  const float* bv  = (const float*)d_in[7];
  const float* ipw = (const float*)d_in[8];
  const float* ipb = (const float*)d_in[9];
  const float* Wo  = (const float*)d_in[10];
  const float* bo  = (const float*)d_in[11];
  const float* Wiv = ipw + 2 * E_DIM * E_DIM;
  const float* biv = ipb + 2 * E_DIM;

  char* ws = (char*)d_ws;
  unsigned short* Xb   = (unsigned short*)(ws);               // 16384x512 bf16, 16 MB
  unsigned short* Wivb = (unsigned short*)(ws + (16 << 20));  // 1024x1024 bf16, 2 MB
  unsigned short* Wob  = (unsigned short*)(ws + (18 << 20));  // 1024x1024 bf16, 2 MB
  unsigned short* WvTb = (unsigned short*)(ws + (20 << 20));  // 512x1024 bf16, 1 MB
  unsigned short* Ttb  = (unsigned short*)(ws + (21 << 20));  // 512x1024 bf16 (T^T)
  unsigned short* Wcb  = (unsigned short*)(ws + (22 << 20));  // 1024x512 bf16
  float* b1 = (float*)(ws + (23 << 20));
  float* bc = (float*)(ws + (23 << 20) + 4096);

  // K1: transpose Wv -> WvT || matvec b1 || cvt vit/Wiv/Wo to bf16
  prep1<<<3328, 256, 0, stream>>>(Wv, WvTb, Wiv, bv, biv, b1, vit, Xb, Wivb, Wo, Wob);

  // K2: T^T (512x1024) = WvT @ Wiv^T  ||  bc = Wo@b1 + bo
  gemm_cv<64, 64, 64, 2, 2, 1, 0><<<128 + 256, 256, 0, stream>>>(
      WvTb, Wivb, nullptr, nullptr, Ttb, 512, 1024, 1024, Wo, b1, bo, bc);

  // K3: Wc (1024x512) = Wo @ T
  gemm_cv<64, 64, 64, 2, 2, 1, 0><<<128, 256, 0, stream>>>(
      Wob, Ttb, nullptr, nullptr, Wcb, 1024, 512, 1024,
      nullptr, nullptr, nullptr, nullptr);

  // K4: out (16384x1024 f32) = Xb @ Wc^T + bc (XCD row-band swizzle)
  gemm_cv<128, 128, 32, 4, 4, 0, 1><<<1024, 256, 0, stream>>>(
      Xb, Wcb, bc, (float*)d_out, nullptr, 16384, 1024, 512,
      nullptr, nullptr, nullptr, nullptr);
}